// Round 4
// baseline (1349.797 us; speedup 1.0000x reference)
//
#include <hip/hip_runtime.h>
#include <hip/hip_bf16.h>

namespace {

using bf16x8 = __attribute__((ext_vector_type(8))) short;
using f32x4  = __attribute__((ext_vector_type(4))) float;

constexpr int NL = 9, S = 7, BB = 8192;
constexpr int G = 8;            // sequences per block
constexpr int M = G * S;        // 56 token rows
constexpr int NT = 512;

// LDS layout (bytes)
constexpr int OFF_F1 = 0;       // fp32 [56][64] swizzled (32B granule)
constexpr int OFF_F2 = 14336;
constexpr int OFF_Q  = 28672;
constexpr int OFF_QB = 43008;   // bf16 [56][64] swizzled (16B granule)
constexpr int OFF_KB = 50176;   // bf16 [112][64] swizzled
constexpr int OFF_VT = 64512;   // bf16 V [64 d][128 kv] swizzled (16B granule)
constexpr int SMEM_TOTAL = 80896;   // <= 81920 -> 2 blocks/CU

__device__ __forceinline__ unsigned short f2bf(float f) {
  union { __hip_bfloat16 h; unsigned short s; } u;
  u.h = __float2bfloat16(f);
  return u.s;
}
__device__ __forceinline__ uint32_t pk2(float a, float b) {
  return (uint32_t)f2bf(a) | ((uint32_t)f2bf(b) << 16);
}
__device__ __forceinline__ int swzS(int r, int c) {   // fp32 [*][64]
  return r * 256 + ((((c >> 3) ^ (r & 7)) << 5) | ((c & 7) << 2));
}
__device__ __forceinline__ int swzB(int r, int c) {   // bf16 [*][64]
  return r * 128 + ((((c >> 3) ^ (r & 7)) << 4) | ((c & 7) << 1));
}
__device__ __forceinline__ int swzV(int d, int kv) {  // bf16 [64][128]
  return d * 256 + ((((kv >> 3) ^ (d & 7)) << 4) | ((kv & 7) << 1));
}
__device__ __forceinline__ int div7(int t) { return (t * 9363) >> 16; }  // t < 56

// state fp32 (swizzled) -> bf16x8 fragment: 8 consecutive k (k0 % 8 == 0)
__device__ __forceinline__ bf16x8 ldStateFrag(const char* base, int r, int k0) {
  const float4* p = (const float4*)(base + r * 256 + (((k0 >> 3) ^ (r & 7)) << 5));
  float4 x = p[0], y = p[1];
  union { bf16x8 v; uint32_t u[4]; } o;
  o.u[0] = pk2(x.x, x.y); o.u[1] = pk2(x.z, x.w);
  o.u[2] = pk2(y.x, y.y); o.u[3] = pk2(y.z, y.w);
  return o.v;
}
__device__ __forceinline__ bf16x8 ldBfFrag(const char* base, int r, int k0) {
  return *(const bf16x8*)(base + r * 128 + (((k0 >> 3) ^ (r & 7)) << 4));
}

struct StvNone { __device__ void operator()(int, int, f32x4) const {} };

// Swapped-operand GEMM over a 64(or 32)-K projection.
// Normal tiles (nt < VNT):   D = W x state^T  -> lane: token = lane&15, 4
//   consecutive features rows -> packed 8B stores; bias float4 into acc.
// V tiles (nt >= VNT):       D = state x W^T  -> lane: feature col, 4 tokens.
template <int MTOT, int NTOT, int KF, int WMG, int WNG, int VNT, bool WS,
          class BLD, class STN, class STV>
__device__ __forceinline__ void gemm_sw(const short* __restrict__ wbf,
                                        const float* __restrict__ wf,
                                        const float* __restrict__ bias,
                                        int ldK, int wid, int lane,
                                        BLD bld, STN stn, STV stv)
{
  const int wm = wid / WNG, wn = wid % WNG;
  const int q = lane & 15, gI = lane >> 4;
  constexpr int MPW = (MTOT + WMG - 1) / WMG;
  constexpr int NPW = NTOT / WNG;
  bf16x8 bfr[MPW][KF];
#pragma unroll
  for (int i = 0; i < MPW; ++i) {
    const int mt = wm * MPW + i;
    if (mt < MTOT) {
#pragma unroll
      for (int kf = 0; kf < KF; ++kf)
        bfr[i][kf] = bld(mt * 16 + q, kf * 32 + gI * 8);
    }
  }
#pragma unroll
  for (int j = 0; j < NPW; ++j) {
    const int nt = wn * NPW + j;
    bf16x8 afr[KF];
#pragma unroll
    for (int kf = 0; kf < KF; ++kf) {
      const int k0 = kf * 32 + gI * 8;
      if constexpr (WS) {
        afr[kf] = *(const bf16x8*)(wbf + (size_t)(nt * 16 + q) * ldK + k0);
      } else {
        const float* wp = wf + (size_t)(nt * 16 + q) * ldK + k0;
        float4 x = *(const float4*)wp, y = *(const float4*)(wp + 4);
        union { bf16x8 v; uint32_t u[4]; } o;
        o.u[0] = pk2(x.x, x.y); o.u[1] = pk2(x.z, x.w);
        o.u[2] = pk2(y.x, y.y); o.u[3] = pk2(y.z, y.w);
        afr[kf] = o.v;
      }
    }
    if (nt < VNT) {
      const float4 b4 = *(const float4*)(bias + nt * 16 + gI * 4);
#pragma unroll
      for (int i = 0; i < MPW; ++i) {
        const int mt = wm * MPW + i;
        if (mt < MTOT) {
          f32x4 acc = { b4.x, b4.y, b4.z, b4.w };
#pragma unroll
          for (int kf = 0; kf < KF; ++kf)
            acc = __builtin_amdgcn_mfma_f32_16x16x32_bf16(afr[kf], bfr[i][kf], acc, 0, 0, 0);
          stn(mt, nt, acc);
        }
      }
    } else {
      const float bv = bias[nt * 16 + q];
#pragma unroll
      for (int i = 0; i < MPW; ++i) {
        const int mt = wm * MPW + i;
        if (mt < MTOT) {
          f32x4 acc = { bv, bv, bv, bv };
#pragma unroll
          for (int kf = 0; kf < KF; ++kf)
            acc = __builtin_amdgcn_mfma_f32_16x16x32_bf16(bfr[i][kf], afr[kf], acc, 0, 0, 0);
          stv(mt, nt, acc);
        }
      }
    }
  }
}

// Attention: wave wid owns sequence g = wid, loops over 4 heads.
template <bool CA_>
__device__ __forceinline__ void attn(char* qb, const char* kb, const char* vt,
                                     int wid, int lane)
{
  const int q = lane & 15, gI = lane >> 4;
  const int g = wid;
  constexpr int KVL = CA_ ? 14 : 7;
#pragma unroll
  for (int h = 0; h < 4; ++h) {
    bf16x8 kfrag = {}, qfrag = {};
    if (gI < 2) {
      int qrow = g * 7 + q; qrow = qrow > 55 ? 55 : qrow;
      qfrag = ldBfFrag(qb, qrow, h * 16 + gI * 8);
      int kvr;
      if constexpr (CA_) {
        kvr = (q < 7) ? (g * 7 + q) : (49 + g * 7 + q);
        kvr = kvr > 111 ? 111 : kvr;
      } else {
        kvr = g * 7 + q; kvr = kvr > 55 ? 55 : kvr;
      }
      kfrag = ldBfFrag(kb, kvr, h * 16 + gI * 8);
    }
    f32x4 s = { 0.f, 0.f, 0.f, 0.f };
    s = __builtin_amdgcn_mfma_f32_16x16x32_bf16(kfrag, qfrag, s, 0, 0, 0);

    float e[4]; float sum = 0.f;
#pragma unroll
    for (int jj = 0; jj < 4; ++jj) {
      const int kvloc = gI * 4 + jj;
      const float tt = fminf(s[jj] * 0.36067376f, 60.f);   // *0.25 * log2(e)
      e[jj] = (kvloc < KVL) ? exp2f(tt) : 0.f;
      sum += e[jj];
    }
    sum += __shfl_xor(sum, 16);
    sum += __shfl_xor(sum, 32);
    const float inv = __builtin_amdgcn_rcpf(sum);

    union { bf16x8 v; uint32_t u[4]; } pb;
    pb.u[0] = pk2(e[0] * inv, e[1] * inv);
    pb.u[1] = pk2(e[2] * inv, e[3] * inv);
    pb.u[2] = 0; pb.u[3] = 0;

    const int d = h * 16 + q;
    const int kv0 = (CA_ ? g * 16 : g * 8) + gI * 4;
    const uint2 vv = *(const uint2*)(vt + swzV(d, kv0));
    union { bf16x8 v; uint32_t u[4]; } va;
    va.u[0] = vv.x; va.u[1] = vv.y; va.u[2] = 0; va.u[3] = 0;

    f32x4 o = { 0.f, 0.f, 0.f, 0.f };
    o = __builtin_amdgcn_mfma_f32_16x16x32_bf16(va.v, pb.v, o, 0, 0, 0);

    if (q < 7) {
      const int tok = g * 7 + q, c0 = h * 16 + gI * 4;
      *(uint2*)(qb + swzB(tok, c0)) = make_uint2(pk2(o[0], o[1]), pk2(o[2], o[3]));
    }
  }
}

// Residual RMW into fp32 swizzled state tile.
template <class BLD, bool WS>
__device__ __forceinline__ void out_proj(char* ST, const short* Wo, const float* Fo,
                                         const float* Bo, int wid, int lane, BLD bldc)
{
  const int q = lane & 15, gI = lane >> 4;
  auto stres = [&](int mt, int nt, f32x4 a) {
    const int tok = mt * 16 + q; if (tok >= M) return;
    const int c0 = nt * 16 + gI * 4;
    float4* p = (float4*)(ST + tok * 256 + (((c0 >> 3) ^ (tok & 7)) << 5) + (c0 & 7) * 4);
    float4 v = *p;
    v.x += a[0]; v.y += a[1]; v.z += a[2]; v.w += a[3];
    *p = v;
  };
  gemm_sw<4, 4, 2, 2, 4, 4, WS>(Wo, Fo, Bo, 64, wid, lane, bldc, stres, StvNone{});
}

// ---------------- self-attention block (state ST updated in place) ------------
template <bool WS>
__device__ __forceinline__ void sa_block(char* ST, char* qb, char* kb, char* vt,
    const short* Wi, const float* Fi, const float* Bi,
    const short* Wo, const float* Fo, const float* Bo,
    int wid, int lane)
{
  const int q = lane & 15, gI = lane >> 4;
  auto bld = [&](int r, int k0) { return ldStateFrag(ST, r > 55 ? 55 : r, k0); };
  auto stn = [&](int mt, int nt, f32x4 a) {        // nt<4: Q, 4..7: K
    const int tok = mt * 16 + q; if (tok >= M) return;
    if (nt < 4) {
      *(uint2*)(qb + swzB(tok, nt * 16 + gI * 4)) =
          make_uint2(pk2(a[0], a[1]), pk2(a[2], a[3]));
    } else {
      *(uint2*)(kb + swzB(tok, (nt - 4) * 16 + gI * 4)) =
          make_uint2(pk2(a[0], a[1]), pk2(a[2], a[3]));
    }
  };
  auto stv = [&](int mt, int nt, f32x4 a) {        // nt>=8: V -> vt[d][kv]
    const int d = (nt - 8) * 16 + q;
#pragma unroll
    for (int jj = 0; jj < 4; ++jj) {
      const int tok = mt * 16 + gI * 4 + jj;
      if (tok < M) {
        const int g = div7(tok);
        *(short*)(vt + swzV(d, g * 8 + (tok - g * 7))) = (short)f2bf(a[jj]);
      }
    }
  };
  gemm_sw<4, 12, 2, 2, 4, 8, WS>(Wi, Fi, Bi, 64, wid, lane, bld, stn, stv);
  __syncthreads();
  attn<false>(qb, kb, vt, wid, lane);
  __syncthreads();
  auto bldc = [&](int r, int k0) { return ldBfFrag(qb, r > 55 ? 55 : r, k0); };
  out_proj<decltype(bldc), WS>(ST, Wo, Fo, Bo, wid, lane, bldc);
  __syncthreads();
}

// ------------- cross-attention K/V projection from one source (SRC=0/1) -------
template <bool WS, int SRC>
__device__ __forceinline__ void ca_kv(const char* SS, char* kb, char* vt,
    const short* Wi, const float* Fi, const float* Bi, int wid, int lane)
{
  const int q = lane & 15, gI = lane >> 4;
  auto bld = [&](int r, int k0) { return ldStateFrag(SS, r > 55 ? 55 : r, k0); };
  auto stk = [&](int mt, int nt, f32x4 a) {      // nt<4: K
    const int tok = mt * 16 + q; if (tok >= M) return;
    *(uint2*)(kb + swzB(tok + SRC * 56, nt * 16 + gI * 4)) =
        make_uint2(pk2(a[0], a[1]), pk2(a[2], a[3]));
  };
  auto stv = [&](int mt, int nt, f32x4 a) {      // nt>=4: V
    const int d = (nt - 4) * 16 + q;
#pragma unroll
    for (int jj = 0; jj < 4; ++jj) {
      const int tok = mt * 16 + gI * 4 + jj;
      if (tok < M) {
        const int g = div7(tok);
        *(short*)(vt + swzV(d, g * 16 + (tok - g * 7) + SRC * 7)) = (short)f2bf(a[jj]);
      }
    }
  };
  gemm_sw<4, 8, 2, 2, 4, 4, WS>(Wi + 4096, Fi + 4096, Bi + 64, 64, wid, lane,
                                bld, stk, stv);
}

template <bool WS>
__global__ __launch_bounds__(NT, 4) void pose_kernel(
    const float* __restrict__ feature1, const float* __restrict__ feature2,
    const float* __restrict__ sa1_win, const float* __restrict__ sa1_bin,
    const float* __restrict__ sa1_wout, const float* __restrict__ sa1_bout,
    const float* __restrict__ sa2_win, const float* __restrict__ sa2_bin,
    const float* __restrict__ sa2_wout, const float* __restrict__ sa2_bout,
    const float* __restrict__ ca_win, const float* __restrict__ ca_bin,
    const float* __restrict__ ca_wout, const float* __restrict__ ca_bout,
    const float* __restrict__ ff_w1, const float* __restrict__ ff_b1,
    const float* __restrict__ ff_w2, const float* __restrict__ ff_b2,
    const float* __restrict__ query_embed,
    const float* __restrict__ fc_rot_w, const float* __restrict__ fc_rot_b,
    const float* __restrict__ fc_trans_w, const float* __restrict__ fc_trans_b,
    const short* __restrict__ wbf, float* __restrict__ out)
{
  extern __shared__ char smem[];
  char* sF1 = smem + OFF_F1;
  char* sF2 = smem + OFF_F2;
  char* sQ  = smem + OFF_Q;
  char* qb  = smem + OFF_QB;
  char* kb  = smem + OFF_KB;
  char* vt  = smem + OFF_VT;

  const int t = threadIdx.x;
  const int wid = t >> 6, lane = t & 63;
  const int q = lane & 15, gI = lane >> 4;
  const int bi = blockIdx.y;
  const int b0 = blockIdx.x * G;

  // zero-init V buffer once (pad slots must be finite: NaN*0 = NaN in MFMA)
  {
    const uint4 z = { 0, 0, 0, 0 };
    for (int i = t; i < 1024; i += NT) ((uint4*)vt)[i] = z;
  }
  // load per-sequence state (coalesced) into swizzled fp32 tiles
  {
    const float* f1p = feature1 + (size_t)b0 * (S * 64);
    const float* f2p = feature2 + (size_t)b0 * (S * 64);
    const float* qe  = query_embed + (size_t)bi * (S * 64);
    for (int idx = t; idx < M * 64; idx += NT) {
      const int r = idx >> 6, c = idx & 63;
      const int s = r - div7(r) * 7;
      *(float*)(sF1 + swzS(r, c)) = f1p[idx];
      *(float*)(sF2 + swzS(r, c)) = f2p[idx];
      *(float*)(sQ + swzS(r, c))  = qe[s * 64 + c];
    }
  }
  __syncthreads();

  for (int li = 0; li < NL; ++li) {
    const int wo = bi * NL + li;

    // ---------- self-attention on f1 ----------
    sa_block<WS>(sF1, qb, kb, vt,
                 wbf + wo * 12288,          sa1_win + wo * 12288,  sa1_bin + wo * 192,
                 wbf + 663552 + wo * 4096,  sa1_wout + wo * 4096,  sa1_bout + wo * 64,
                 wid, lane);
    // ---------- self-attention on f2 ----------
    sa_block<WS>(sF2, qb, kb, vt,
                 wbf + 221184 + wo * 12288, sa2_win + wo * 12288,  sa2_bin + wo * 192,
                 wbf + 737280 + wo * 4096,  sa2_wout + wo * 4096,  sa2_bout + wo * 64,
                 wid, lane);

    // ---------- cross-attention ----------
    {
      const short* Wi = wbf + 442368 + wo * 12288;
      const float* Fi = ca_win + wo * 12288;
      const float* Bi = ca_bin + wo * 192;
      auto bldq = [&](int r, int k0) { return ldStateFrag(sQ, r > 55 ? 55 : r, k0); };
      auto stq = [&](int mt, int nt, f32x4 a) {
        const int tok = mt * 16 + q; if (tok >= M) return;
        *(uint2*)(qb + swzB(tok, nt * 16 + gI * 4)) =
            make_uint2(pk2(a[0], a[1]), pk2(a[2], a[3]));
      };
      gemm_sw<4, 4, 2, 2, 4, 4, WS>(Wi, Fi, Bi, 64, wid, lane, bldq, stq, StvNone{});
      ca_kv<WS, 0>(sF1, kb, vt, Wi, Fi, Bi, wid, lane);
      ca_kv<WS, 1>(sF2, kb, vt, Wi, Fi, Bi, wid, lane);
      __syncthreads();
      attn<true>(qb, kb, vt, wid, lane);
      __syncthreads();
      auto bldc = [&](int r, int k0) { return ldBfFrag(qb, r > 55 ? 55 : r, k0); };
      out_proj<decltype(bldc), WS>(sQ, wbf + 811008 + wo * 4096, ca_wout + wo * 4096,
                                   ca_bout + wo * 64, wid, lane, bldc);
      __syncthreads();
    }

    // ---------- FFN ----------
    {
      auto bldq = [&](int r, int k0) { return ldStateFrag(sQ, r > 55 ? 55 : r, k0); };
      auto sth = [&](int mt, int nt, f32x4 a) {        // relu -> qb cols 0..31
        const int tok = mt * 16 + q; if (tok >= M) return;
        *(uint2*)(qb + swzB(tok, nt * 16 + gI * 4)) =
            make_uint2(pk2(fmaxf(a[0], 0.f), fmaxf(a[1], 0.f)),
                       pk2(fmaxf(a[2], 0.f), fmaxf(a[3], 0.f)));
      };
      gemm_sw<4, 2, 2, 4, 2, 2, WS>(wbf + 884736 + wo * 2048, ff_w1 + wo * 2048,
                                    ff_b1 + wo * 32, 64, wid, lane, bldq, sth, StvNone{});
      __syncthreads();
      auto bldh = [&](int r, int k0) { return ldBfFrag(qb, r > 55 ? 55 : r, k0); };
      auto stres = [&](int mt, int nt, f32x4 a) {
        const int tok = mt * 16 + q; if (tok >= M) return;
        const int c0 = nt * 16 + gI * 4;
        float4* p = (float4*)(sQ + tok * 256 + (((c0 >> 3) ^ (tok & 7)) << 5) + (c0 & 7) * 4);
        float4 v = *p;
        v.x += a[0]; v.y += a[1]; v.z += a[2]; v.w += a[3];
        *p = v;
      };
      gemm_sw<4, 4, 1, 2, 4, 4, WS>(wbf + 921600 + wo * 2048, ff_w2 + wo * 2048,
                                    ff_b2 + wo * 64, 32, wid, lane, bldh, stres, StvNone{});
      __syncthreads();
    }
  }

  // ---------- pose head ----------
  float* cs = (float*)qb;   // [8][64] fp32 scratch (qb is free now)
  {
    const int g = t >> 6, c = t & 63;   // 512 threads == 8*64 items
    float a = 0.f;
#pragma unroll
    for (int s = 0; s < 7; ++s) a += *(const float*)(sQ + swzS(g * 7 + s, c));
    cs[t] = a;
  }
  __syncthreads();
  const int ncols = bi ? 3 : 4;
  if (t < G * ncols) {
    const int g = t / ncols, cc = t - g * ncols;
    const float* wv = bi ? (fc_trans_w + cc * 64) : (fc_rot_w + cc * 64);
    float acc = 0.f;
#pragma unroll
    for (int k = 0; k < 64; ++k) acc += cs[g * 64 + k] * wv[k];
    const float bb = bi ? fc_trans_b[cc] : fc_rot_b[cc];
    out[(size_t)(b0 + g) * 7 + (bi ? 4 : 0) + cc] = acc * (1.f / 7.f) + bb;
  }
}

// Convert all weight matrices fp32 -> bf16 into workspace (once per call).
__global__ void prep_kernel(const float* __restrict__ a0, const float* __restrict__ a1,
                            const float* __restrict__ a2, const float* __restrict__ a3,
                            const float* __restrict__ a4, const float* __restrict__ a5,
                            const float* __restrict__ a6, const float* __restrict__ a7,
                            short* __restrict__ dst)
{
  for (int i = blockIdx.x * blockDim.x + threadIdx.x; i < 958464;
       i += gridDim.x * blockDim.x) {
    const float* s; int j;
    if      (i < 221184) { s = a0; j = i; }
    else if (i < 442368) { s = a1; j = i - 221184; }
    else if (i < 663552) { s = a2; j = i - 442368; }
    else if (i < 737280) { s = a3; j = i - 663552; }
    else if (i < 811008) { s = a4; j = i - 737280; }
    else if (i < 884736) { s = a5; j = i - 811008; }
    else if (i < 921600) { s = a6; j = i - 884736; }
    else                 { s = a7; j = i - 921600; }
    dst[i] = (short)f2bf(s[j]);
  }
}

} // namespace

extern "C" void kernel_launch(void* const* d_in, const int* in_sizes, int n_in,
                              void* d_out, int out_size, void* d_ws, size_t ws_size,
                              hipStream_t stream)
{
  const float* feature1    = (const float*)d_in[0];
  const float* feature2    = (const float*)d_in[1];
  const float* sa1_win     = (const float*)d_in[2];
  const float* sa1_bin     = (const float*)d_in[3];
  const float* sa1_wout    = (const float*)d_in[4];
  const float* sa1_bout    = (const float*)d_in[5];
  const float* sa2_win     = (const float*)d_in[6];
  const float* sa2_bin     = (const float*)d_in[7];
  const float* sa2_wout    = (const float*)d_in[8];
  const float* sa2_bout    = (const float*)d_in[9];
  const float* ca_win      = (const float*)d_in[10];
  const float* ca_bin      = (const float*)d_in[11];
  const float* ca_wout     = (const float*)d_in[12];
  const float* ca_bout     = (const float*)d_in[13];
  const float* ff_w1       = (const float*)d_in[14];
  const float* ff_b1       = (const float*)d_in[15];
  const float* ff_w2       = (const float*)d_in[16];
  const float* ff_b2       = (const float*)d_in[17];
  const float* query_embed = (const float*)d_in[18];
  const float* fc_rot_w    = (const float*)d_in[19];
  const float* fc_rot_b    = (const float*)d_in[20];
  const float* fc_trans_w  = (const float*)d_in[21];
  const float* fc_trans_b  = (const float*)d_in[22];

  const bool ws_ok = (d_ws != nullptr) && (ws_size >= (size_t)958464 * 2);
  dim3 grid(BB / G, 2);

  if (ws_ok) {
    prep_kernel<<<dim3(936), 512, 0, stream>>>(sa1_win, sa2_win, ca_win,
                                               sa1_wout, sa2_wout, ca_wout,
                                               ff_w1, ff_w2, (short*)d_ws);
    hipFuncSetAttribute(reinterpret_cast<const void*>(&pose_kernel<true>),
                        hipFuncAttributeMaxDynamicSharedMemorySize, SMEM_TOTAL);
    pose_kernel<true><<<grid, NT, SMEM_TOTAL, stream>>>(
        feature1, feature2,
        sa1_win, sa1_bin, sa1_wout, sa1_bout,
        sa2_win, sa2_bin, sa2_wout, sa2_bout,
        ca_win, ca_bin, ca_wout, ca_bout,
        ff_w1, ff_b1, ff_w2, ff_b2,
        query_embed, fc_rot_w, fc_rot_b, fc_trans_w, fc_trans_b,
        (const short*)d_ws, (float*)d_out);
  } else {
    hipFuncSetAttribute(reinterpret_cast<const void*>(&pose_kernel<false>),
                        hipFuncAttributeMaxDynamicSharedMemorySize, SMEM_TOTAL);
    pose_kernel<false><<<grid, NT, SMEM_TOTAL, stream>>>(
        feature1, feature2,
        sa1_win, sa1_bin, sa1_wout, sa1_bout,
        sa2_win, sa2_bin, sa2_wout, sa2_bout,
        ca_win, ca_bin, ca_wout, ca_bout,
        ff_w1, ff_b1, ff_w2, ff_b2,
        query_embed, fc_rot_w, fc_rot_b, fc_trans_w, fc_trans_b,
        (const short*)d_ws, (float*)d_out);
  }
}